// Round 1
// baseline (184.789 us; speedup 1.0000x reference)
//
#include <hip/hip_runtime.h>

#define DD   32     // input size
#define HH   256    // hidden size
#define BB   4096   // batch
#define RR   4      // rows per wave (one wave per block)
#define EPSF 1e-12f

// Degrees: deg_in[i] = i+1 ; deg_h[h] = (h % 31) + 1.
// h0[h]  = relu(b0[h] + sum_{i <= deg_h[h]-1} y_i W0[i,h])
// h1[h'] = relu(b1[h'] + sum_{deg_h[h] <= deg_h[h']} h0[h] W1[h,h'])
// out[d] = b2[d] + sum_{deg_h[h'] <= d} h1[h'] W2[h',d]
// Sequential forward substitution: at step d, hiddens with deg==d finalize.

__global__ __launch_bounds__(64, 1) void made_inv(
    const float* __restrict__ x,
    const float* __restrict__ muW0, const float* __restrict__ mub0,
    const float* __restrict__ muW1, const float* __restrict__ mub1,
    const float* __restrict__ muW2, const float* __restrict__ mub2,
    const float* __restrict__ lvW0, const float* __restrict__ lvb0,
    const float* __restrict__ lvW1, const float* __restrict__ lvb1,
    const float* __restrict__ lvW2, const float* __restrict__ lvb2,
    float* __restrict__ out)
{
    const int lane    = threadIdx.x;       // 0..63
    const int rowBase = blockIdx.x * RR;   // 4 rows per block
    const int hb      = lane << 2;         // base hidden index (4 slots/lane)

    int deg[4];
    #pragma unroll
    for (int s = 0; s < 4; ++s) deg[s] = ((hb + s) % 31) + 1;

    const float* Wp0[2] = {muW0, lvW0};
    const float* Bp0[2] = {mub0, lvb0};
    const float* Wp1[2] = {muW1, lvW1};
    const float* Bp1[2] = {mub1, lvb1};
    const float* Wp2[2] = {muW2, lvW2};

    // per-lane state: [net][slot][row]
    float h0pre[2][4][RR];
    float h1pre[2][4][RR];
    float r1   [2][4][RR];   // relu(h1) snapshot at finalize; 0 until then
    float yprev[RR];
    float lsum [RR];

    #pragma unroll
    for (int n = 0; n < 2; ++n) {
        const float4 b0v = *reinterpret_cast<const float4*>(Bp0[n] + hb);
        const float4 b1v = *reinterpret_cast<const float4*>(Bp1[n] + hb);
        const float b0a[4] = {b0v.x, b0v.y, b0v.z, b0v.w};
        const float b1a[4] = {b1v.x, b1v.y, b1v.z, b1v.w};
        #pragma unroll
        for (int s = 0; s < 4; ++s)
            #pragma unroll
            for (int r = 0; r < RR; ++r) {
                h0pre[n][s][r] = b0a[s];
                h1pre[n][s][r] = b1a[s];
                r1[n][s][r]    = 0.f;
            }
    }
    #pragma unroll
    for (int r = 0; r < RR; ++r) { yprev[r] = 0.f; lsum[r] = 0.f; }

    // broadcast scratch for newly-finalized relu(h0): [net][row][k<=9 (pad 12)]
    __shared__ float lds_a[2][RR][12];

    for (int d = 0; d < DD; ++d) {
        if (d >= 1) {
            // ---- h0pre += y_{d-1} * W0[d-1, :]  (unpredicated: safe, see above)
            #pragma unroll
            for (int n = 0; n < 2; ++n) {
                const float4 w0 = *reinterpret_cast<const float4*>(
                    Wp0[n] + (d - 1) * HH + hb);
                const float w0a[4] = {w0.x, w0.y, w0.z, w0.w};
                #pragma unroll
                for (int s = 0; s < 4; ++s)
                    #pragma unroll
                    for (int r = 0; r < RR; ++r)
                        h0pre[n][s][r] = fmaf(yprev[r], w0a[s], h0pre[n][s][r]);
            }
            // ---- finalize h0 with deg==d -> LDS (h = d-1 + 31k)
            #pragma unroll
            for (int n = 0; n < 2; ++n)
                #pragma unroll
                for (int s = 0; s < 4; ++s)
                    if (deg[s] == d) {
                        const int k = (hb + s - (d - 1)) / 31;
                        #pragma unroll
                        for (int r = 0; r < RR; ++r)
                            lds_a[n][r][k] = fmaxf(h0pre[n][s][r], 0.f);
                    }
            __syncthreads();

            // ---- h1pre += relu(h0[deg==d]) * W1[deg==d, :]
            const bool nine = (d <= 8);   // k=8 exists only for d<=8
            #pragma unroll
            for (int n = 0; n < 2; ++n) {
                const float* W1p = Wp1[n] + (size_t)(d - 1) * HH + hb;
                float4 w1v[9];
                #pragma unroll
                for (int k = 0; k < 8; ++k)
                    w1v[k] = *reinterpret_cast<const float4*>(W1p + k * 31 * HH);
                if (nine)
                    w1v[8] = *reinterpret_cast<const float4*>(W1p + 8 * 31 * HH);
                #pragma unroll
                for (int r = 0; r < RR; ++r) {
                    const float4 a03 = *reinterpret_cast<const float4*>(&lds_a[n][r][0]);
                    const float4 a47 = *reinterpret_cast<const float4*>(&lds_a[n][r][4]);
                    const float  av[8] = {a03.x, a03.y, a03.z, a03.w,
                                          a47.x, a47.y, a47.z, a47.w};
                    #pragma unroll
                    for (int k = 0; k < 8; ++k) {
                        const float wk[4] = {w1v[k].x, w1v[k].y, w1v[k].z, w1v[k].w};
                        #pragma unroll
                        for (int s = 0; s < 4; ++s)
                            h1pre[n][s][r] = fmaf(av[k], wk[s], h1pre[n][s][r]);
                    }
                    if (nine) {
                        const float a8 = lds_a[n][r][8];
                        const float wk[4] = {w1v[8].x, w1v[8].y, w1v[8].z, w1v[8].w};
                        #pragma unroll
                        for (int s = 0; s < 4; ++s)
                            h1pre[n][s][r] = fmaf(a8, wk[s], h1pre[n][s][r]);
                    }
                }
            }
            // ---- snapshot relu(h1) for slots finalizing now
            #pragma unroll
            for (int n = 0; n < 2; ++n)
                #pragma unroll
                for (int s = 0; s < 4; ++s)
                    if (deg[s] == d)
                        #pragma unroll
                        for (int r = 0; r < RR; ++r)
                            r1[n][s][r] = fmaxf(h1pre[n][s][r], 0.f);
            __syncthreads();   // LDS reads of step d done before step d+1 writes
        }

        // ---- output d: reduce r1 * W2[:, d] over all 256 hiddens
        float w2v[2][4];
        #pragma unroll
        for (int n = 0; n < 2; ++n)
            #pragma unroll
            for (int s = 0; s < 4; ++s)
                w2v[n][s] = Wp2[n][(hb + s) * DD + d];

        float red[2][RR];
        #pragma unroll
        for (int n = 0; n < 2; ++n)
            #pragma unroll
            for (int r = 0; r < RR; ++r) {
                float p = 0.f;
                #pragma unroll
                for (int s = 0; s < 4; ++s)
                    p = fmaf(r1[n][s][r], w2v[n][s], p);
                red[n][r] = p;
            }
        #pragma unroll
        for (int m = 1; m < 64; m <<= 1)
            #pragma unroll
            for (int n = 0; n < 2; ++n)
                #pragma unroll
                for (int r = 0; r < RR; ++r)
                    red[n][r] += __shfl_xor(red[n][r], m, 64);

        const float b2m = mub2[d];
        const float b2l = lvb2[d];
        #pragma unroll
        for (int r = 0; r < RR; ++r) {
            const float mu     = red[0][r] + b2m;
            const float logstd = 0.5f * (red[1][r] + b2l);
            lsum[r] += logstd;
            const float denom = __expf(logstd) + EPSF;
            const float yd = (x[(rowBase + r) * DD + d] - mu) / denom;
            yprev[r] = yd;
            if (lane == 0) out[(rowBase + r) * DD + d] = yd;
        }
    }

    if (lane == 0) {
        #pragma unroll
        for (int r = 0; r < RR; ++r)
            out[BB * DD + rowBase + r] = lsum[r];
    }
}

extern "C" void kernel_launch(void* const* d_in, const int* in_sizes, int n_in,
                              void* d_out, int out_size, void* d_ws, size_t ws_size,
                              hipStream_t stream) {
    const float* x    = (const float*)d_in[0];
    const float* muW0 = (const float*)d_in[1];
    const float* mub0 = (const float*)d_in[2];
    const float* muW1 = (const float*)d_in[3];
    const float* mub1 = (const float*)d_in[4];
    const float* muW2 = (const float*)d_in[5];
    const float* mub2 = (const float*)d_in[6];
    const float* lvW0 = (const float*)d_in[7];
    const float* lvb0 = (const float*)d_in[8];
    const float* lvW1 = (const float*)d_in[9];
    const float* lvb1 = (const float*)d_in[10];
    const float* lvW2 = (const float*)d_in[11];
    const float* lvb2 = (const float*)d_in[12];
    float* out = (float*)d_out;

    dim3 grid(BB / RR);   // 1024 blocks, one wave each
    dim3 block(64);
    made_inv<<<grid, block, 0, stream>>>(x,
        muW0, mub0, muW1, mub1, muW2, mub2,
        lvW0, lvb0, lvW1, lvb1, lvW2, lvb2,
        out);
}